// Round 7
// baseline (182.998 us; speedup 1.0000x reference)
//
#include <hip/hip_runtime.h>

// OccupancyGridForestAS — R10: access-class separation.
//
// Post-mortem chain: R9 (4-deep ILP, half TLP) neutral -> MLP saturated.
// R6 algebra: pure sequential read sweep ran ~6 TB/s, so no universal read
// ceiling; but every kernel MIXING random gathers with streams lands at
// 2.1-2.5 TB/s regardless of bytes moved (90-170 MB all take 42-47 us).
// Model: per-CU line-fill (MSHR ~64) pool shared; a random gather holds a
// slot ~900cy (row-miss), stream lines ~150-200cy -> gathers hog the pool
// and drag the co-resident stream down to gather-class throughput.
//
// R10: only 12.5% of points gather (64/512 valid cells -> 524K gathers).
//  * K1 (stream-only): read pts (nt), compute, write zeros to out, compact
//    valid (pid, flatIdx) entries into 64 per-tree workspace buckets via
//    LDS histogram + 64 padded global atomics. ZERO gathers -> stream rate.
//  * K2 (gather-only): 1024 blocks, tree = blk&63 -> all blocks of tree t
//    share blk%8 -> XCD-pinned; each XCD touches 8 trees (~3.4 MB unique
//    lines, fits 4 MB L2) -> row locality + L2 reuse -> short MSHR occupancy.
//  * Workspace: 4 KB padded counters + 64*12288 int2 entries (~6.3 MB);
//    hipMemsetAsync zeroes counters (graph-capture-safe). Falls back to the
//    R7 pipelined single kernel if ws_size is too small.

#define LDIM 8
#define RES  64
#define NTREE 64
#define MAXPT 12288          // entry slots per tree (mean 8192, SD ~90)
#define CNT_STRIDE 16        // ints between counters (64B padding)
#define STAGE_CAP 16         // staged entries per tree per block (mean 4)

typedef float v4f __attribute__((ext_vector_type(4)));

// Compute flat gather index + tree + validity for 4 points in 3 float4s.
// Float op sequence replicated exactly from the reference.
__device__ __forceinline__ void compute4(
    const int* __restrict__ slut, v4f q0, v4f q1, v4f q2,
    int ii[4], int tr[4], bool valid[4])
{
    const float xs[4] = {q0.x, q0.w, q1.z, q2.y};
    const float ys[4] = {q0.y, q1.x, q1.w, q2.z};
    const float zs[4] = {q0.z, q1.y, q2.x, q2.w};
#pragma unroll
    for (int k = 0; k < 4; ++k) {
        float x = xs[k], y = ys[k], z = zs[k];
        int bx = (int)floorf(x);
        int by = (int)floorf(y);
        int bz = (int)floorf(z);
        bool in_dom = (bx >= 0) & (bx < LDIM) &
                      (by >= 0) & (by < LDIM) &
                      (bz >= 0) & (bz < LDIM);
        int cx = min(max(bx, 0), LDIM - 1);
        int cy = min(max(by, 0), LDIM - 1);
        int cz = min(max(bz, 0), LDIM - 1);

        int bidx = slut[(cx * LDIM + cy) * LDIM + cz];
        bool v = in_dom & (bidx >= 0);

        float bxf = 2.0f * (x - (float)cx) - 1.0f;
        float byf = 2.0f * (y - (float)cy) - 1.0f;
        float bzf = 2.0f * (z - (float)cz) - 1.0f;
        float tx = (bxf * 0.5f + 0.5f) * (float)RES;
        float ty = (byf * 0.5f + 0.5f) * (float)RES;
        float tz = (bzf * 0.5f + 0.5f) * (float)RES;
        int vx = min(max((int)floorf(tx), 0), RES - 1);
        int vy = min(max((int)floorf(ty), 0), RES - 1);
        int vz = min(max((int)floorf(tz), 0), RES - 1);

        int sb = v ? bidx : 0;
        ii[k] = ((sb * RES + vx) * RES + vy) * RES + vz;  // < 2^24
        tr[k] = sb;
        valid[k] = v;
    }
}

// --- K1: stream-class. pts -> zeros in out + compacted per-tree entries. ---
__global__ __launch_bounds__(256) void phase1_kernel(
    const v4f*   __restrict__ pts4,
    const float* __restrict__ grid,      // only for impossible-overflow path
    const int*   __restrict__ lookup,
    v4f*         __restrict__ out4,
    float*       __restrict__ out,       // alias of out4, fallback path
    int*         __restrict__ counters,  // [NTREE * CNT_STRIDE], zeroed
    int2*        __restrict__ entries,   // [NTREE * MAXPT]
    int T)                               // total threads; chunks j and j+T
{
    __shared__ int  slut[LDIM * LDIM * LDIM];   // 2 KB
    __shared__ int  lcnt[NTREE];
    __shared__ int  gbase[NTREE];
    __shared__ int2 staged[NTREE * STAGE_CAP];  // 8 KB

    ((int2*)slut)[threadIdx.x] = ((const int2*)lookup)[threadIdx.x];
    if (threadIdx.x < NTREE) lcnt[threadIdx.x] = 0;
    __syncthreads();  // before any global load: vmcnt drain is free

    int tid = threadIdx.x;
    int j = blockIdx.x * blockDim.x + tid;

    // R7's pipelined pts loads: both chunks issued up front, nt (read-once).
    const v4f* pA = pts4 + 3 * j;
    v4f a0 = __builtin_nontemporal_load(pA + 0);
    v4f a1 = __builtin_nontemporal_load(pA + 1);
    v4f a2 = __builtin_nontemporal_load(pA + 2);
    const v4f* pB = pts4 + 3 * (j + T);
    v4f b0 = __builtin_nontemporal_load(pB + 0);
    v4f b1 = __builtin_nontemporal_load(pB + 1);
    v4f b2 = __builtin_nontemporal_load(pB + 2);

    // Chunk A: compute, stage valid entries, store zeros.
    {
        int ii[4], tr[4]; bool vv[4];
        compute4(slut, a0, a1, a2, ii, tr, vv);
        v4f oz = {0.0f, 0.0f, 0.0f, 0.0f};
#pragma unroll
        for (int k = 0; k < 4; ++k) {
            if (vv[k]) {
                int lp = atomicAdd(&lcnt[tr[k]], 1);
                if (lp < STAGE_CAP) staged[tr[k] * STAGE_CAP + lp] = make_int2(4 * j + k, ii[k]);
                else oz[k] = grid[ii[k]];   // astronomically rare belt
            }
        }
        out4[j] = oz;   // regular store: lines stay cached for K2's scatter RMW
    }
    // Chunk B.
    {
        int ii[4], tr[4]; bool vv[4];
        compute4(slut, b0, b1, b2, ii, tr, vv);
        v4f oz = {0.0f, 0.0f, 0.0f, 0.0f};
#pragma unroll
        for (int k = 0; k < 4; ++k) {
            if (vv[k]) {
                int lp = atomicAdd(&lcnt[tr[k]], 1);
                if (lp < STAGE_CAP) staged[tr[k] * STAGE_CAP + lp] = make_int2(4 * (j + T) + k, ii[k]);
                else oz[k] = grid[ii[k]];
            }
        }
        out4[j + T] = oz;
    }
    __syncthreads();  // staging complete

    // Reserve per-tree global ranges: 64 atomics to 64B-padded counters.
    if (tid < NTREE) {
        int c = lcnt[tid];
        gbase[tid] = (c > 0) ? atomicAdd(&counters[tid * CNT_STRIDE], c) : 0;
    }
    __syncthreads();

    // Copy staged entries to global buckets. b = tid&63, slots strided by 4.
    {
        int b = tid & 63;
        int c = min(lcnt[b], STAGE_CAP);
        for (int s = tid >> 6; s < c; s += 4) {
            int g = gbase[b] + s;
            int2 e = staged[b * STAGE_CAP + s];
            if (g < MAXPT) entries[b * MAXPT + g] = e;
            else out[e.x] = grid[e.y];   // impossible-overflow belt
        }
    }
}

// --- K2: gather-class only. tree = blk&63 -> XCD-pinned per tree. ---
__global__ __launch_bounds__(256) void phase2_kernel(
    const float* __restrict__ grid,
    const int*   __restrict__ counters,
    const int2*  __restrict__ entries,
    float*       __restrict__ out)
{
    int t = blockIdx.x & 63;            // tree; all its blocks share blk%8 (XCD)
    int w = blockIdx.x >> 6;            // 0..15 within tree
    int cnt = counters[t * CNT_STRIDE];
    if (cnt > MAXPT) cnt = MAXPT;
    const int2* eb = entries + t * MAXPT;
    for (int i = w * 256 + (int)threadIdx.x; i < cnt; i += 16 * 256) {
        int2 e = eb[i];                 // coalesced 8B, L3-warm (written by K1)
        out[e.x] = grid[e.y];           // gather random within tree's 1 MB
    }
}

// --- Fallback: R7's pipelined single kernel (used if workspace too small). ---
__global__ __launch_bounds__(256, 8) void occ_forest_fallback(
    const v4f* __restrict__ pts4, const float* __restrict__ grid,
    const int* __restrict__ lookup, v4f* __restrict__ out4, int T)
{
    __shared__ int slut[LDIM * LDIM * LDIM];
    ((int2*)slut)[threadIdx.x] = ((const int2*)lookup)[threadIdx.x];
    __syncthreads();
    int j = blockIdx.x * blockDim.x + threadIdx.x;
    const v4f* pA = pts4 + 3 * j;
    v4f a0 = __builtin_nontemporal_load(pA + 0);
    v4f a1 = __builtin_nontemporal_load(pA + 1);
    v4f a2 = __builtin_nontemporal_load(pA + 2);
    const v4f* pB = pts4 + 3 * (j + T);
    v4f b0 = __builtin_nontemporal_load(pB + 0);
    v4f b1 = __builtin_nontemporal_load(pB + 1);
    v4f b2 = __builtin_nontemporal_load(pB + 2);

    int iiA[4], trA[4]; bool vA[4];
    compute4(slut, a0, a1, a2, iiA, trA, vA);
    float gA[4];
#pragma unroll
    for (int k = 0; k < 4; ++k) gA[k] = grid[vA[k] ? iiA[k] : 0];
    int iiB[4], trB[4]; bool vB[4];
    compute4(slut, b0, b1, b2, iiB, trB, vB);
    float gB[4];
#pragma unroll
    for (int k = 0; k < 4; ++k) gB[k] = grid[vB[k] ? iiB[k] : 0];

    v4f oA, oB;
#pragma unroll
    for (int k = 0; k < 4; ++k) oA[k] = vA[k] ? gA[k] : 0.0f;
#pragma unroll
    for (int k = 0; k < 4; ++k) oB[k] = vB[k] ? gB[k] : 0.0f;
    __builtin_nontemporal_store(oA, out4 + j);
    __builtin_nontemporal_store(oB, out4 + j + T);
}

extern "C" void kernel_launch(void* const* d_in, const int* in_sizes, int n_in,
                              void* d_out, int out_size, void* d_ws, size_t ws_size,
                              hipStream_t stream) {
    const float* pts    = (const float*)d_in[0];
    const float* grid   = (const float*)d_in[1];
    const int*   lookup = (const int*)d_in[2];

    int T = out_size / 8;                       // 524288 threads, 8 pts each
    int threads = 256;
    int blocks = T / threads;                   // 2048

    size_t cnt_bytes = (size_t)NTREE * CNT_STRIDE * sizeof(int);   // 4 KB
    size_t ent_bytes = (size_t)NTREE * MAXPT * sizeof(int2);       // ~6.3 MB
    size_t need = cnt_bytes + ent_bytes;

    if (ws_size >= need && d_ws != nullptr) {
        int*  counters = (int*)d_ws;
        int2* entries  = (int2*)((char*)d_ws + cnt_bytes);
        hipMemsetAsync(d_ws, 0, cnt_bytes, stream);  // zero counters (capture-safe)
        phase1_kernel<<<blocks, threads, 0, stream>>>(
            (const v4f*)pts, grid, lookup,
            (v4f*)d_out, (float*)d_out, counters, entries, T);
        phase2_kernel<<<1024, threads, 0, stream>>>(
            grid, counters, entries, (float*)d_out);
    } else {
        occ_forest_fallback<<<blocks, threads, 0, stream>>>(
            (const v4f*)pts, grid, lookup, (v4f*)d_out, T);
    }
}

// Round 8
// 149.911 us; speedup vs baseline: 1.2207x; 1.2207x over previous
//
#include <hip/hip_runtime.h>

// OccupancyGridForestAS — R11: sorted gathers kept, compaction fan-out fixed.
//
// R10 findings (first visible per-class rows):
//  * phase1 (stream-only, zero gathers) = 49 us @ 1.1 TB/s -> MSHR-mixing
//    theory DEAD. Its cost: per-tree entry scatter (64 regions/block, 8B
//    uncoalesced writes -> ~67 MB RMW traffic) + LDS staging machinery.
//  * phase2 (tree-sorted, XCD-pinned gathers) ~= 4-6 us. Sorted gathers are
//    nearly free (~5 TB/s line rate). R8 algebra: unsorted gathers ~30 us.
//
// R11: bucket by XCD (tree&7, 8 buckets) instead of tree (64):
//  * per-block fan-out 64 -> 8 contiguous full-line runs (512B) -> no RMW,
//    fully coalesced entry writes (~8 MB clean).
//  * K2 keeps XCD-pinning (bucket x on blocks with blk%8==x): each XCD
//    gathers from 8 trees ~= 3.25 MB unique lines -> L2-resident reuse.
//  * Fixed per-block slot regions (cap SCAP, ~6-sigma) -> ZERO global
//    atomics, ZERO memset launch. Spill belt: direct gather in phase1.
//  * Regular (non-nt) loads everywhere for clean FETCH accounting (R10
//    showed nt loads vanish from FETCH_SIZE).

#define LDIM 8
#define RES  64
#define NB   8    // buckets = XCDs

typedef float v4f __attribute__((ext_vector_type(4)));

__device__ __forceinline__ void compute4(
    const int* __restrict__ slut, v4f q0, v4f q1, v4f q2,
    int ii[4], int tr[4], bool valid[4])
{
    const float xs[4] = {q0.x, q0.w, q1.z, q2.y};
    const float ys[4] = {q0.y, q1.x, q1.w, q2.z};
    const float zs[4] = {q0.z, q1.y, q2.x, q2.w};
#pragma unroll
    for (int k = 0; k < 4; ++k) {
        float x = xs[k], y = ys[k], z = zs[k];
        int bx = (int)floorf(x);
        int by = (int)floorf(y);
        int bz = (int)floorf(z);
        bool in_dom = (bx >= 0) & (bx < LDIM) &
                      (by >= 0) & (by < LDIM) &
                      (bz >= 0) & (bz < LDIM);
        int cx = min(max(bx, 0), LDIM - 1);
        int cy = min(max(by, 0), LDIM - 1);
        int cz = min(max(bz, 0), LDIM - 1);

        int bidx = slut[(cx * LDIM + cy) * LDIM + cz];
        bool v = in_dom & (bidx >= 0);

        // Reference float op sequence, replicated exactly.
        float bxf = 2.0f * (x - (float)cx) - 1.0f;
        float byf = 2.0f * (y - (float)cy) - 1.0f;
        float bzf = 2.0f * (z - (float)cz) - 1.0f;
        float tx = (bxf * 0.5f + 0.5f) * (float)RES;
        float ty = (byf * 0.5f + 0.5f) * (float)RES;
        float tz = (bzf * 0.5f + 0.5f) * (float)RES;
        int vx = min(max((int)floorf(tx), 0), RES - 1);
        int vy = min(max((int)floorf(ty), 0), RES - 1);
        int vz = min(max((int)floorf(tz), 0), RES - 1);

        int sb = v ? bidx : 0;
        ii[k] = ((sb * RES + vx) * RES + vy) * RES + vz;  // < 2^24
        tr[k] = sb;
        valid[k] = v;
    }
}

// --- K1: stream-class. pts -> zeros in out + 8 coalesced bucket runs. ---
template<int SCAP>
__global__ __launch_bounds__(256) void phase1_kernel(
    const v4f*   __restrict__ pts4,
    const float* __restrict__ grid,     // spill belt only
    const int*   __restrict__ lookup,
    v4f*         __restrict__ out4,
    int*         __restrict__ cnt,      // [nblk * NB]
    int2*        __restrict__ ent,      // [NB][nblk][SCAP]
    int T)                              // total threads; chunks j and j+T
{
    __shared__ int  slut[LDIM * LDIM * LDIM];  // 2 KB
    __shared__ int2 staged[NB * SCAP];         // <= 4 KB
    __shared__ int  lcnt[NB];

    ((int2*)slut)[threadIdx.x] = ((const int2*)lookup)[threadIdx.x];
    if (threadIdx.x < NB) lcnt[threadIdx.x] = 0;
    __syncthreads();  // before any global load: vmcnt drain is free

    int tid = threadIdx.x;
    int blk = blockIdx.x;
    int j = blk * 256 + tid;

    // Both pts chunks issued up front (R7 pipelining), regular cached loads.
    const v4f* pA = pts4 + 3 * j;
    v4f a0 = pA[0], a1 = pA[1], a2 = pA[2];
    const v4f* pB = pts4 + 3 * (j + T);
    v4f b0 = pB[0], b1 = pB[1], b2 = pB[2];

    // Chunk A: compute, stage valid entries per XCD-bucket, store zeros.
    {
        int ii[4], tr[4]; bool vv[4];
        compute4(slut, a0, a1, a2, ii, tr, vv);
        v4f oz = {0.0f, 0.0f, 0.0f, 0.0f};
#pragma unroll
        for (int k = 0; k < 4; ++k) {
            if (vv[k]) {
                int x = tr[k] & (NB - 1);
                int lp = atomicAdd(&lcnt[x], 1);
                if (lp < SCAP) staged[x * SCAP + lp] = make_int2(4 * j + k, ii[k]);
                else oz[k] = grid[ii[k]];   // ~6-sigma spill belt
            }
        }
        out4[j] = oz;
    }
    // Chunk B.
    {
        int ii[4], tr[4]; bool vv[4];
        compute4(slut, b0, b1, b2, ii, tr, vv);
        v4f oz = {0.0f, 0.0f, 0.0f, 0.0f};
#pragma unroll
        for (int k = 0; k < 4; ++k) {
            if (vv[k]) {
                int x = tr[k] & (NB - 1);
                int lp = atomicAdd(&lcnt[x], 1);
                if (lp < SCAP) staged[x * SCAP + lp] = make_int2(4 * (j + T) + k, ii[k]);
                else oz[k] = grid[ii[k]];
            }
        }
        out4[j + T] = oz;
    }
    __syncthreads();

    // Write 8 contiguous SCAP-entry runs (full 64B lines, coalesced; garbage
    // slots masked by cnt in K2) + per-bucket counts. No atomics, no RMW.
    int nblk = gridDim.x;
#pragma unroll
    for (int i = tid; i < NB * SCAP; i += 256) {
        int x = i / SCAP, s = i % SCAP;
        ent[((size_t)x * nblk + blk) * SCAP + s] = staged[i];
    }
    if (tid < NB) cnt[blk * NB + tid] = min(lcnt[tid], SCAP);
}

// --- K2: gather-class. Bucket x on blocks blk%8==x -> XCD-pinned. ---
template<int SCAP>
__global__ __launch_bounds__(256) void phase2_kernel(
    const float* __restrict__ grid,
    const int*   __restrict__ cnt,
    const int2*  __restrict__ ent,
    float*       __restrict__ out,
    int nblk1)
{
    const int NPOS = NB * SCAP;           // entry-positions per K2 block
    int x = blockIdx.x & (NB - 1);        // bucket == XCD (blk%8 round-robin)
    int g = blockIdx.x >> 3;              // slot-group: 8 phase1-blocks
    // ent[x][slot][e] with slots g*8..g*8+7 is linear: eb[i], i in [0,NPOS).
    const int2* eb = ent + (size_t)x * nblk1 * SCAP + (size_t)g * NPOS;
    int t = threadIdx.x;

    int i0 = t, i1 = t + 256;
    bool q1 = i1 < NPOS;
    int2 e0 = eb[i0];
    int2 e1 = q1 ? eb[i1] : make_int2(0, 0);
    int c0 = cnt[(g * NB + i0 / SCAP) * NB + x];
    int c1 = q1 ? cnt[(g * NB + i1 / SCAP) * NB + x] : 0;
    bool p0 = (i0 % SCAP) < c0;
    bool p1 = q1 & ((i1 % SCAP) < c1);

    // Both gathers in flight; garbage entries never dereferenced (select 0).
    float v0 = grid[p0 ? e0.y : 0];
    float v1 = grid[p1 ? e1.y : 0];
    if (p0) out[e0.x] = v0;
    if (p1) out[e1.x] = v1;
}

// --- Fallback: R7's pipelined single kernel (workspace too small). ---
__global__ __launch_bounds__(256, 8) void occ_forest_fallback(
    const v4f* __restrict__ pts4, const float* __restrict__ grid,
    const int* __restrict__ lookup, v4f* __restrict__ out4, int T)
{
    __shared__ int slut[LDIM * LDIM * LDIM];
    ((int2*)slut)[threadIdx.x] = ((const int2*)lookup)[threadIdx.x];
    __syncthreads();
    int j = blockIdx.x * blockDim.x + threadIdx.x;
    const v4f* pA = pts4 + 3 * j;
    v4f a0 = pA[0], a1 = pA[1], a2 = pA[2];
    const v4f* pB = pts4 + 3 * (j + T);
    v4f b0 = pB[0], b1 = pB[1], b2 = pB[2];

    int iiA[4], trA[4]; bool vA[4];
    compute4(slut, a0, a1, a2, iiA, trA, vA);
    float gA[4];
#pragma unroll
    for (int k = 0; k < 4; ++k) gA[k] = grid[vA[k] ? iiA[k] : 0];
    int iiB[4], trB[4]; bool vB[4];
    compute4(slut, b0, b1, b2, iiB, trB, vB);
    float gB[4];
#pragma unroll
    for (int k = 0; k < 4; ++k) gB[k] = grid[vB[k] ? iiB[k] : 0];

    v4f oA, oB;
#pragma unroll
    for (int k = 0; k < 4; ++k) oA[k] = vA[k] ? gA[k] : 0.0f;
#pragma unroll
    for (int k = 0; k < 4; ++k) oB[k] = vB[k] ? gB[k] : 0.0f;
    out4[j] = oA;
    out4[j + T] = oB;
}

extern "C" void kernel_launch(void* const* d_in, const int* in_sizes, int n_in,
                              void* d_out, int out_size, void* d_ws, size_t ws_size,
                              hipStream_t stream) {
    const float* pts    = (const float*)d_in[0];
    const float* grid   = (const float*)d_in[1];
    const int*   lookup = (const int*)d_in[2];

    int T = out_size / 8;                      // 524288 threads, 8 pts each
    int threads = 256;
    int nblk = T / threads;                    // 2048 (exact)

    size_t cnt_b = (size_t)nblk * NB * sizeof(int);  // 64 KB
    auto ent_b = [&](int scap) { return (size_t)NB * nblk * scap * sizeof(int2); };

    if (d_ws && ws_size >= cnt_b + ent_b(64)) {        // 8.06 MB
        int*  cnt = (int*)d_ws;
        int2* ent = (int2*)((char*)d_ws + cnt_b);
        phase1_kernel<64><<<nblk, threads, 0, stream>>>(
            (const v4f*)pts, grid, lookup, (v4f*)d_out, cnt, ent, T);
        phase2_kernel<64><<<nblk, threads, 0, stream>>>(
            grid, cnt, ent, (float*)d_out, nblk);
    } else if (d_ws && ws_size >= cnt_b + ent_b(48)) { // 6.06 MB (fits R10's ws)
        int*  cnt = (int*)d_ws;
        int2* ent = (int2*)((char*)d_ws + cnt_b);
        phase1_kernel<48><<<nblk, threads, 0, stream>>>(
            (const v4f*)pts, grid, lookup, (v4f*)d_out, cnt, ent, T);
        phase2_kernel<48><<<nblk, threads, 0, stream>>>(
            grid, cnt, ent, (float*)d_out, nblk);
    } else {
        occ_forest_fallback<<<nblk, threads, 0, stream>>>(
            (const v4f*)pts, grid, lookup, (v4f*)d_out, T);
    }
}